// Round 3
// baseline (237.507 us; speedup 1.0000x reference)
//
#include <hip/hip_runtime.h>
#include <hip/hip_bf16.h>

// ---------------------------------------------------------------------------
// WaveletNauralNet: 9-level DWT -> 8 band reconstructions (h: 2048x32768,
// linear in x1) -> relu -> W0 (181x32768) -> relu -> W1 (13x181) -> relu ->
// W2 (10x13).
//   K1: fused [per-row analysis] + [W0 fp32->fp16 convert] heterogeneous grid
//   K2 (THIS ROUND): register-chained synthesis, <=2 stages per cascade:
//       - L2/L3/L4: SINGLE stage, no LDS/barrier: per-thread backward windows
//         (init/withcd/final fused in registers, global in -> f16 out)
//       - L5..L9: stage A = collapsed chain (4/6/8 levels in registers,
//         129/65 threads) -> penultimate 2052/1030 array in swizzled LDS;
//         stage B = full-width final/finpair (256 threads)
//       Stage-slots 25 -> 14, barriers 17 -> 5, LDS halved (s2 dropped).
//       Window/pad bounds verified: all global over-reads land in the >=2
//       float inter-level pads; garbage only feeds store-guarded discards.
//   K3: BM=256 split-K MFMA GEMM, 512 thr, double-buffered LDS (112KB),
//       1 block/CU, staged bytes 235MB (R2 form).
//   K4: reduce partials + MLP layers 1..2 (R8 form)
// D rows repacked: DOFF multiples of 4 (16B-aligned float4 loads), DROW 4160.
// ---------------------------------------------------------------------------

typedef _Float16 f16x8 __attribute__((ext_vector_type(8)));
typedef _Float16 f16x4v __attribute__((ext_vector_type(4)));
typedef float f32x4 __attribute__((ext_vector_type(4)));

#define WV_THREADS 256
#define DROW 4160   // per-row float stride of packed d1..d9 (16B-aligned levels)
#define NSPLIT 32
#define KCHUNK 1024
#define GEMM_BM 256

// reconstruction filters
#define L0 0.23037781330885523f
#define L1 0.7148465705525415f
#define L2f 0.6308807679295904f
#define L3 -0.02798376941698385f
#define L4 -0.18703481171888114f
#define L5 0.030841381835986965f
#define L6 0.032883011666982945f
#define L7 -0.010597401784997278f

#define H0 -0.010597401784997278f
#define H1 -0.032883011666982945f
#define H2 0.030841381835986965f
#define H3 0.18703481171888114f
#define H4 -0.02798376941698385f
#define H5 -0.6308807679295904f
#define H6 0.7148465705525415f
#define H7 -0.23037781330885523f

__constant__ constexpr int cNL[10]   = {4096, 2051, 1029, 518, 262, 134, 70, 38, 22, 14};
// 16B-aligned packing; pads absorb window over-reads (>=2 floats each level)
__constant__ constexpr int cDOFF[10] = {0, 0, 2052, 3084, 3604, 3868, 4004, 4076, 4116, 4140};

__device__ __forceinline__ int ext_idx(int j, int n) {
  return (j < 6) ? (5 - j) : ((j < n + 6) ? (j - 6) : (2 * n + 5 - j));
}

// one DWT level, 2 outputs per thread, stride-1 lanes. (analysis, unchanged)
__device__ __forceinline__ void dwt2(const float* a, float* anext, float* d,
                                     int n, int m, bool store_a) {
  const int ng = (m + 1) >> 1;
  for (int g = threadIdx.x; g < ng; g += WV_THREADS) {
    float w[10];
    if (g >= 2 && 4 * g + 9 <= n + 5) {
      const float2* af = (const float2*)a + (2 * g - 3);
      float2 b0 = af[0], b1 = af[1], b2 = af[2], b3 = af[3], b4 = af[4];
      w[0] = b0.x; w[1] = b0.y; w[2] = b1.x; w[3] = b1.y; w[4] = b2.x;
      w[5] = b2.y; w[6] = b3.x; w[7] = b3.y; w[8] = b4.x; w[9] = b4.y;
    } else {
#pragma unroll
      for (int q = 0; q < 10; ++q) {
        int j = 4 * g + q;
        int jm = n + 12;
        if (j > jm) j = jm;
        w[q] = a[ext_idx(j, n)];
      }
    }
    float sl0 = w[0]*L0 + w[1]*L1 + w[2]*L2f + w[3]*L3 + w[4]*L4 + w[5]*L5 + w[6]*L6 + w[7]*L7;
    float sh0 = w[0]*H0 + w[1]*H1 + w[2]*H2  + w[3]*H3 + w[4]*H4 + w[5]*H5 + w[6]*H6 + w[7]*H7;
    float sl1 = w[2]*L0 + w[3]*L1 + w[4]*L2f + w[5]*L3 + w[6]*L4 + w[7]*L5 + w[8]*L6 + w[9]*L7;
    float sh1 = w[2]*H0 + w[3]*H1 + w[4]*H2  + w[5]*H3 + w[6]*H4 + w[7]*H5 + w[8]*H6 + w[9]*H7;
    if (2 * g + 1 < m) {
      if (store_a) *(float2*)(anext + 2 * g) = make_float2(sl0, sl1);
      *(float2*)(d + 2 * g) = make_float2(sh0, sh1);
    } else {
      if (store_a) anext[2 * g] = sl0;
      d[2 * g] = sh0;
    }
  }
}

// ---------------------------------------------------------------------------
// Swizzled LDS float4 slot accessors: slot u -> u ^ ((u>>3)&7). Bijective
// within each aligned 8-slot (128B) row; conflict-free b128 reads/writes.
#define SWZ(u) ((u) ^ (((u) >> 3) & 7))
__device__ __forceinline__ const float4* lds4c(const float* b, int s) {
  return (const float4*)b + SWZ(s);
}
__device__ __forceinline__ float4* lds4(float* b, int s) {
  return (float4*)b + SWZ(s);
}

// ---------------------------------------------------------------------------
// IDWT level primitives (register arrays, fully unrolled).
// v[2q]   = e(q) = a[q+3]L0 + a[q+2]L2 + a[q+1]L4 + a[q]L6  (+ d-H terms)
// v[2q+1] = o(q) = a[q+3]L1 + a[q+2]L3 + a[q+1]L5 + a[q]L7  (+ d-H terms)
template <int NP>
__device__ __forceinline__ void lvlL(const float* a, float* v) {  // nocd
#pragma unroll
  for (int q = 0; q < NP; ++q) {
    v[2*q]   = a[q+3]*L0 + a[q+2]*L2f + a[q+1]*L4 + a[q]*L6;
    v[2*q+1] = a[q+3]*L1 + a[q+2]*L3  + a[q+1]*L5 + a[q]*L7;
  }
}
template <int NP>
__device__ __forceinline__ void lvlH(const float* d, float* v) {  // init (cd only)
#pragma unroll
  for (int q = 0; q < NP; ++q) {
    v[2*q]   = d[q+3]*H0 + d[q+2]*H2 + d[q+1]*H4 + d[q]*H6;
    v[2*q+1] = d[q+3]*H1 + d[q+2]*H3 + d[q+1]*H5 + d[q]*H7;
  }
}
template <int NP>
__device__ __forceinline__ void lvlLH(const float* a, const float* d, float* v) {  // withcd
#pragma unroll
  for (int q = 0; q < NP; ++q) {
    v[2*q]   = a[q+3]*L0 + a[q+2]*L2f + a[q+1]*L4 + a[q]*L6
             + d[q+3]*H0 + d[q+2]*H2  + d[q+1]*H4 + d[q]*H6;
    v[2*q+1] = a[q+3]*L1 + a[q+2]*L3  + a[q+1]*L5 + a[q]*L7
             + d[q+3]*H1 + d[q+2]*H3  + d[q+1]*H5 + d[q]*H7;
  }
}

// global window readers
__device__ __forceinline__ void g7(const float* p, int s, float* w) {
#pragma unroll
  for (int i = 0; i < 7; ++i) w[i] = p[s + i];
}
__device__ __forceinline__ void g8f2(const float* p, int s, float* w) {  // s even
#pragma unroll
  for (int i = 0; i < 4; ++i) {
    float2 v = *(const float2*)(p + s + 2 * i);
    w[2*i] = v.x; w[2*i+1] = v.y;
  }
}
__device__ __forceinline__ void g12f4(const float* p, int s, float* w) {  // s%4==0
#pragma unroll
  for (int i = 0; i < 3; ++i) {
    float4 v = *(const float4*)(p + s + 4 * i);
    w[4*i] = v.x; w[4*i+1] = v.y; w[4*i+2] = v.z; w[4*i+3] = v.w;
  }
}

// relu + f16 store of 16 interleaved e/o values
__device__ __forceinline__ void store16(_Float16* outg, int t, const float* v) {
  f16x8 h0, h1;
#pragma unroll
  for (int i = 0; i < 8; ++i) h0[i] = (_Float16)fmaxf(v[i], 0.f);
#pragma unroll
  for (int i = 0; i < 8; ++i) h1[i] = (_Float16)fmaxf(v[8 + i], 0.f);
  *(f16x8*)(outg + 16 * t) = h0;
  *(f16x8*)(outg + 16 * t + 8) = h1;
}

// ---------------------------------------------------------------------------
// Single-stage cascades (no LDS, no barrier). Window bounds verified:
// fin2: d2 [4t,4t+12) <= 3083 pad ok; d1 [8t,8t+12) <= idx 2051 pad ok.
__device__ __forceinline__ void fin2(const float* d2, const float* d1, _Float16* og) {
  const int t = threadIdx.x;
  float dw[12];  g12f4(d2, 4 * t, dw);
  float mid[12]; lvlH<6>(dw, mid);           // 2052-arr vals [8t, 8t+12)
  float d1w[12]; g12f4(d1, 8 * t, d1w);
  float v[16];   lvlLH<8>(mid, d1w, v);      // final with cd = d1
  store16(og, t, v);
}

// fin3: init(d3)->1030(trunc 1029), wc(d2)->2052(2051), final.
__device__ __forceinline__ void fin3(const float* d3, const float* d2, _Float16* og) {
  const int t = threadIdx.x;
  float dw[8];   g8f2(d3, 2 * t, dw);        // d3[2t..2t+7]
  float v0[10];  lvlH<5>(dw, v0);            // init vals [4t, 4t+10)
  float d2w[12]; g12f4(d2, 4 * t, d2w);
  float v1[12];  lvlLH<6>(v0, d2w, v1);      // wc vals [8t, 8t+12)
  float v[16];   lvlL<8>(v1, v);
  store16(og, t, v);
}

// fin4: init(d4)->518, wc(d3)->1030(1029), nocd->2052(2051), final.
__device__ __forceinline__ void fin4(const float* d4, const float* d3, _Float16* og) {
  const int t = threadIdx.x;
  float dw[7];   g7(d4, t, dw);              // d4[t..t+6] (len 262: exact fit)
  float v0[8];   lvlH<4>(dw, v0);            // [2t, 2t+8)
  float d3w[8];  g8f2(d3, 2 * t, d3w);
  float v1[10];  lvlLH<5>(v0, d3w, v1);      // [4t, 4t+10)
  float v2[12];  lvlL<6>(v1, v2);            // [8t, 8t+12)
  float v[16];   lvlL<8>(v2, v);
  store16(og, t, v);
}

// ---------------------------------------------------------------------------
// Collapsed A-chains -> swizzled LDS (penultimate array).
// chainA4: init(dL), wc(dm), nocd, nocd(out). L5: NG=129 (->2052); L6: 65 (->1030).
template <int NG>
__device__ __forceinline__ void chainA4(const float* dL, const float* dm, float* outl) {
  const int t = threadIdx.x;
  if (t >= NG) return;
  float dw[7];  g7(dL, t, dw);
  float v0[8];  lvlH<4>(dw, v0);             // [2t, 2t+8)
  float dmw[8]; g8f2(dm, 2 * t, dmw);
  float v1[10]; lvlLH<5>(v0, dmw, v1);       // [4t, 4t+10)
  float v2[12]; lvlL<6>(v1, v2);             // [8t, 8t+12)
  float v[16];  lvlL<8>(v2, v);              // vals [16t, 16t+16)
#pragma unroll
  for (int j = 0; j < 4; ++j)
    *lds4(outl, 4 * t + j) = make_float4(v[4*j], v[4*j+1], v[4*j+2], v[4*j+3]);
}

// chainA6: init, wc, nocd x4. L7: NG=129 (->2052); L8: 65 (->1030).
template <int NG>
__device__ __forceinline__ void chainA6(const float* dL, const float* dm, float* outl) {
  const int t = threadIdx.x;
  if (t >= NG) return;
  const int s1 = t >> 1, s2 = s1 >> 1;
  float dw[7];  g7(dL, s2, dw);
  float u0[8];  lvlH<4>(dw, u0);             // [2s2, 2s2+8)
  float dmw[7]; g7(dm, s1, dmw);
  float u1[8];  lvlLH<4>(u0 + (s1 & 1), dmw, u1);  // pairs [s1,+4) -> [2s1,+8)
  float u2[8];  lvlL<4>(u1 + (t & 1), u2);   // pairs [t,+4)  -> [2t, 2t+8)
  float u3[10]; lvlL<5>(u2, u3);             // [4t, 4t+10)
  float u4[12]; lvlL<6>(u3, u4);             // [8t, 8t+12)
  float v[16];  lvlL<8>(u4, v);
#pragma unroll
  for (int j = 0; j < 4; ++j)
    *lds4(outl, 4 * t + j) = make_float4(v[4*j], v[4*j+1], v[4*j+2], v[4*j+3]);
}

// chainA8: init, wc, nocd x6. L9: NG=129 (->2052).
template <int NG>
__device__ __forceinline__ void chainA8(const float* dL, const float* dm, float* outl) {
  const int t = threadIdx.x;
  if (t >= NG) return;
  const int s1 = t >> 1, s2 = s1 >> 1, s3 = s2 >> 1, s4 = s3 >> 1;
  float dw[7];  g7(dL, s4, dw);
  float u0[8];  lvlH<4>(dw, u0);             // [2s4, +8)
  float dmw[7]; g7(dm, s3, dmw);
  float u1[8];  lvlLH<4>(u0 + (s3 & 1), dmw, u1);  // [2s3, +8)
  float u2[8];  lvlL<4>(u1 + (s2 & 1), u2);  // [2s2, +8)
  float u3[8];  lvlL<4>(u2 + (s1 & 1), u3);  // [2s1, +8)
  float u4[8];  lvlL<4>(u3 + (t & 1), u4);   // [2t, +8)
  float u5[10]; lvlL<5>(u4, u5);             // [4t, +10)
  float u6[12]; lvlL<6>(u5, u6);             // [8t, +12)
  float v[16];  lvlL<8>(u6, v);
#pragma unroll
  for (int j = 0; j < 4; ++j)
    *lds4(outl, 4 * t + j) = make_float4(v[4*j], v[4*j+1], v[4*j+2], v[4*j+3]);
}

// ---------------------------------------------------------------------------
// Stage B: full-width finishers reading swizzled LDS.
// finalB: 2052-array (valid 2051) -> 4096 out.
__device__ __forceinline__ void finalB(const float* s, _Float16* og) {
  const int t = threadIdx.x;
  float w[12];
  float4 a = *lds4c(s, 2*t), b = *lds4c(s, 2*t + 1), c = *lds4c(s, 2*t + 2);
  w[0]=a.x; w[1]=a.y; w[2]=a.z; w[3]=a.w; w[4]=b.x; w[5]=b.y; w[6]=b.z; w[7]=b.w;
  w[8]=c.x; w[9]=c.y; w[10]=c.z; w[11]=c.w;
  float v[16]; lvlL<8>(w, v);
  store16(og, t, v);
}

// finpairB: 1030-array (valid 1029) -> 2052(2051) -> 4096 out.
__device__ __forceinline__ void finpairB(const float* s, _Float16* og) {
  const int t = threadIdx.x;
  float w[12];
  float4 a = *lds4c(s, t), b = *lds4c(s, t + 1), c = *lds4c(s, t + 2);
  w[0]=a.x; w[1]=a.y; w[2]=a.z; w[3]=a.w; w[4]=b.x; w[5]=b.y; w[6]=b.z; w[7]=b.w;
  w[8]=c.x; w[9]=c.y; w[10]=c.z; w[11]=c.w;
  float r[12]; lvlL<6>(w, r);    // mid vals [8t, 8t+12)
  float v[16]; lvlL<8>(r, v);
  store16(og, t, v);
}

// ---------------------------------------------------------------------------
// Fused: blocks [0,2048) = analysis rows; blocks [2048, 2048+6144) = W0 cvt.
__global__ __launch_bounds__(WV_THREADS) void wv_analysis_cvt(
    const float* __restrict__ x, float* __restrict__ dG,
    const float* __restrict__ W0, _Float16* __restrict__ Bw) {
  __shared__ float r1[4104];
  __shared__ float r2[2056];
  const int tid = threadIdx.x;

  if (blockIdx.x >= 2048) {  // ---- cvt path ----
    size_t i = ((size_t)(blockIdx.x - 2048) * 256 + tid) * 4;
    int rowc = (int)(i >> 15);
    f16x4v h;
    if (rowc < 181) {
      const float4 v = *(const float4*)(W0 + i);
      h[0] = (_Float16)v.x; h[1] = (_Float16)v.y;
      h[2] = (_Float16)v.z; h[3] = (_Float16)v.w;
    } else {
      h[0] = (_Float16)0.f; h[1] = (_Float16)0.f;
      h[2] = (_Float16)0.f; h[3] = (_Float16)0.f;
    }
    *(f16x4v*)(Bw + i) = h;
    return;
  }

  const int NLa[10]  = {4096, 2051, 1029, 518, 262, 134, 70, 38, 22, 14};
  const int DOFF[10] = {0, 0, 2052, 3084, 3604, 3868, 4004, 4076, 4116, 4140};
  const int LOFF[10] = {0, 0, 1036, 520, 2068, 1040, 2332, 1176, 2404, 1216};
  const int row = blockIdx.x;

  const float4* xr = (const float4*)(x + (size_t)row * 4096);
  for (int i = tid; i < 1024; i += WV_THREADS) ((float4*)r1)[i] = xr[i];
  __syncthreads();

  float* dr = dG + (size_t)row * DROW;
  dwt2(r1, r2, dr + DOFF[1], NLa[0], NLa[1], true);
  __syncthreads();
  const float* ap = r2;
  float* an = r1;
  for (int lev = 2; lev <= 9; ++lev) {
    float* dbuf = ((lev & 1) ? r2 : r1) + LOFF[lev];
    dwt2(ap, an, dbuf, NLa[lev - 1], NLa[lev], lev < 9);
    __syncthreads();
    const float* t = ap; ap = an; an = (float*)t;
  }
  for (int lev = 2; lev <= 9; ++lev) {
    const float* src = ((lev & 1) ? r2 : r1) + LOFF[lev];
    float* dst = dr + DOFF[lev];
    const int n = NLa[lev];
    for (int i = 2 * tid; i + 1 < n; i += 2 * WV_THREADS)
      *(float2*)(dst + i) = *(const float2*)(src + i);
    if ((n & 1) && tid == 0) dst[n - 1] = src[n - 1];
  }
}

// ---------------------------------------------------------------------------
// Synthesis: one block per (row, L=2+blockIdx.y). L2-4 barrier-free.
__global__ __launch_bounds__(WV_THREADS, 6) void wv_synth(
    const float* __restrict__ dG, _Float16* __restrict__ A) {
  __shared__ alignas(16) float s1[2080];   // 520 float4 slots
  const int row = blockIdx.x;
  const float* dr = dG + (size_t)row * DROW;
  _Float16* og = A + (size_t)row * 32768 + (size_t)blockIdx.y * 4096;
  switch (blockIdx.y) {
    case 0: fin2(dr + cDOFF[2], dr + cDOFF[1], og); break;
    case 1: fin3(dr + cDOFF[3], dr + cDOFF[2], og); break;
    case 2: fin4(dr + cDOFF[4], dr + cDOFF[3], og); break;
    case 3: chainA4<129>(dr + cDOFF[5], dr + cDOFF[4], s1); __syncthreads();
            finalB(s1, og); break;
    case 4: chainA4<65>(dr + cDOFF[6], dr + cDOFF[5], s1); __syncthreads();
            finpairB(s1, og); break;
    case 5: chainA6<129>(dr + cDOFF[7], dr + cDOFF[6], s1); __syncthreads();
            finalB(s1, og); break;
    case 6: chainA6<65>(dr + cDOFF[8], dr + cDOFF[7], s1); __syncthreads();
            finpairB(s1, og); break;
    default: chainA8<129>(dr + cDOFF[9], dr + cDOFF[8], s1); __syncthreads();
            finalB(s1, og); break;
  }
}

// ---------------------------------------------------------------------------
__device__ __forceinline__ void load_lds16(const void* g, void* l) {
  __builtin_amdgcn_global_load_lds((__attribute__((address_space(1))) unsigned int*)g,
                                   (__attribute__((address_space(3))) unsigned int*)l,
                                   16, 0, 0);
}

// C(2048x192) += A(2048x32768,f16) * Bw(192x32768,f16)^T, fp32 split-K
// partials. BM=256, 8 waves, grid (8 m, 32 k) = 256 blocks = 1/CU.
// Double-buffered LDS 2-phase pipeline (R2 form).
__global__ __launch_bounds__(512, 2) void gemm_kernel(
    const _Float16* __restrict__ A, const _Float16* __restrict__ Bw,
    float* __restrict__ P) {
  __shared__ _Float16 As[2][GEMM_BM * 64];  // 2 x 32 KB
  __shared__ _Float16 Bs[2][192 * 64];      // 2 x 24 KB  (total 112 KB)
  const int tid = threadIdx.x;
  const int lane = tid & 63;
  const int wave = tid >> 6;          // 0..7
  const int m0 = blockIdx.x * GEMM_BM;
  const int k_idx = blockIdx.y;
  const int k0 = k_idx * KCHUNK;

  f32x4 acc[2][12];
#pragma unroll
  for (int mt = 0; mt < 2; ++mt)
#pragma unroll
    for (int nt = 0; nt < 12; ++nt) acc[mt][nt] = (f32x4){0.f, 0.f, 0.f, 0.f};

  auto stage = [&](int ks, int b) {
    const int kbase = k0 + (ks << 6);
#pragma unroll
    for (int t = 0; t < 4; ++t) {
      int c = wave * 4 + t;
      int g = (c << 6) + lane;
      int r = g >> 3, cs = g & 7;
      const _Float16* gp = A + (size_t)(m0 + r) * 32768 + kbase + ((cs ^ (r & 7)) << 3);
      load_lds16(gp, (char*)As[b] + ((size_t)c << 10));
    }
#pragma unroll
    for (int t = 0; t < 3; ++t) {
      int c = wave * 3 + t;
      int g = (c << 6) + lane;
      int r = g >> 3, cs = g & 7;
      const _Float16* gp = Bw + (size_t)r * 32768 + kbase + ((cs ^ (r & 7)) << 3);
      load_lds16(gp, (char*)Bs[b] + ((size_t)c << 10));
    }
  };

  stage(0, 0);
  __syncthreads();

  for (int ks = 0; ks < (KCHUNK >> 6); ++ks) {
    const int cur = ks & 1;
    if (ks + 1 < (KCHUNK >> 6)) stage(ks + 1, cur ^ 1);
#pragma unroll
    for (int kk = 0; kk < 2; ++kk) {
      const int chunk = kk * 4 + (lane >> 4);
      f16x8 af[2];
#pragma unroll
      for (int mt = 0; mt < 2; ++mt) {
        int r = wave * 32 + mt * 16 + (lane & 15);
        af[mt] = *(const f16x8*)(As[cur] + r * 64 + ((chunk ^ (r & 7)) << 3));
      }
#pragma unroll
      for (int nt = 0; nt < 12; ++nt) {
        int rb = nt * 16 + (lane & 15);
        f16x8 bf = *(const f16x8*)(Bs[cur] + rb * 64 + ((chunk ^ (rb & 7)) << 3));
        acc[0][nt] = __builtin_amdgcn_mfma_f32_16x16x32_f16(af[0], bf, acc[0][nt], 0, 0, 0);
        acc[1][nt] = __builtin_amdgcn_mfma_f32_16x16x32_f16(af[1], bf, acc[1][nt], 0, 0, 0);
      }
    }
    __syncthreads();
  }

  float* Pp = P + ((size_t)k_idx * 2048 + m0) * 192;
#pragma unroll
  for (int mt = 0; mt < 2; ++mt)
#pragma unroll
    for (int nt = 0; nt < 12; ++nt)
#pragma unroll
      for (int r4 = 0; r4 < 4; ++r4) {
        int rr = wave * 32 + mt * 16 + ((lane >> 4) << 2) + r4;
        int cc = nt * 16 + (lane & 15);
        Pp[(size_t)rr * 192 + cc] = acc[mt][nt][r4];
      }
}

// ---------------------------------------------------------------------------
// P reduce: 4 wave-groups x 8 splits, coalesced; then layers 1..2. (R8 form.)
__global__ __launch_bounds__(256) void mlp_kernel(
    const float* __restrict__ P, const float* __restrict__ b0,
    const float* __restrict__ W1, const float* __restrict__ b1,
    const float* __restrict__ W2, const float* __restrict__ b2,
    float* __restrict__ out) {
  __shared__ float part[4][193];
  __shared__ float h1[192];
  __shared__ float h2[13];
  const int row = blockIdx.x;
  const int t = threadIdx.x;
  const int g = t >> 6;
  const int l = t & 63;

  float a0 = 0.f, a1 = 0.f, a2 = 0.f;
  for (int si = 0; si < NSPLIT / 4; ++si) {
    int s = g + (si << 2);
    const float* Pr = P + ((size_t)s * 2048 + row) * 192;
    a0 += Pr[l]; a1 += Pr[64 + l]; a2 += Pr[128 + l];
  }
  part[g][l] = a0; part[g][64 + l] = a1; part[g][128 + l] = a2;
  __syncthreads();

  if (t < 192) {
    float v = part[0][t] + part[1][t] + part[2][t] + part[3][t];
    h1[t] = (t < 181) ? fmaxf(v + b0[t], 0.f) : 0.f;
  }
  __syncthreads();

#pragma unroll
  for (int r = 0; r < 4; ++r) {
    int j = g + (r << 2);
    if (j < 13) {
      float v = 0.f;
#pragma unroll
      for (int q = 0; q < 3; ++q) {
        int n = l + (q << 6);
        if (n < 181) v += h1[n] * W1[j * 181 + n];
      }
      for (int off = 32; off >= 1; off >>= 1) v += __shfl_down(v, off);
      if (l == 0) h2[j] = fmaxf(v + b1[j], 0.f);
    }
  }
  __syncthreads();

  if (t < 10) {
    float c = b2[t];
#pragma unroll
    for (int j = 0; j < 13; ++j) c += h2[j] * W2[t * 13 + j];
    out[(size_t)row * 10 + t] = c;
  }
}

// ---------------------------------------------------------------------------
extern "C" void kernel_launch(void* const* d_in, const int* in_sizes, int n_in,
                              void* d_out, int out_size, void* d_ws, size_t ws_size,
                              hipStream_t stream) {
  const float* x1 = (const float*)d_in[0];
  const float* W0 = (const float*)d_in[3];
  const float* b0 = (const float*)d_in[4];
  const float* W1 = (const float*)d_in[5];
  const float* b1 = (const float*)d_in[6];
  const float* W2 = (const float*)d_in[7];
  const float* b2 = (const float*)d_in[8];
  float* out = (float*)d_out;

  char* ws = (char*)d_ws;
  const size_t A_BYTES = (size_t)2048 * 32768 * 2;
  const size_t B_BYTES = (size_t)192 * 32768 * 2;
  _Float16* Afeat = (_Float16*)ws;
  _Float16* Bw = (_Float16*)(ws + A_BYTES);
  // D (2048*4160*4 = 34 MB) aliases P (50 MB): D dead before gemm writes P.
  float* Dq = (float*)(ws + A_BYTES + B_BYTES);
  float* P = (float*)(ws + A_BYTES + B_BYTES);

  wv_analysis_cvt<<<2048 + 6144, WV_THREADS, 0, stream>>>(x1, Dq, W0, Bw);
  dim3 sg(2048, 8);
  wv_synth<<<sg, WV_THREADS, 0, stream>>>(Dq, Afeat);
  dim3 gg(2048 / GEMM_BM, NSPLIT);
  gemm_kernel<<<gg, 512, 0, stream>>>(Afeat, Bw, P);
  mlp_kernel<<<2048, 256, 0, stream>>>(P, b0, W1, b1, W2, b2, out);
}

// Round 4
// 222.112 us; speedup vs baseline: 1.0693x; 1.0693x over previous
//
#include <hip/hip_runtime.h>
#include <hip/hip_bf16.h>

// ---------------------------------------------------------------------------
// WaveletNauralNet: 9-level DWT -> 8 band reconstructions (h: 2048x32768,
// linear in x1) -> relu -> W0 (181x32768) -> relu -> W1 (13x181) -> relu ->
// W2 (10x13).
//   K1: fused [per-row analysis] + [W0 fp32->fp16 convert] heterogeneous grid
//   K2 (THIS ROUND - hybrid): L2/L3/L4 single-stage register fins (R3 form,
//       shallow chains, full 256 threads, no LDS/barrier - PASSED R3);
//       L5..L9 revert to R1 proven cascades (initpair/pair/finpair +
//       XOR-swizzled LDS; R3's deep chainA6/A8 spilled: WRITE_SIZE +31MB).
//       launch_bounds(256,8) restored (VGPR cap 64, no spill).
//   K3 (THIS ROUND): counted-vmcnt GEMM pipeline (T4). R2's form drained
//       vmcnt(0) at __syncthreads each tile (next-tile loads included) ->
//       no overlap. Now: stage(ks+1) -> s_waitcnt vmcnt(7) (tile ks
//       resident, tile ks+1's 7 loads stay in flight ACROSS the barrier)
//       -> raw s_barrier -> MFMA -> raw s_barrier. Epilogue peels last
//       tile with vmcnt(0). Staged 235MB -> ~40us target.
//   K4: reduce partials + MLP layers 1..2 (R8 form)
// D rows repacked: DOFF multiples of 4 (16B-aligned float4 loads), DROW 4160.
// ---------------------------------------------------------------------------

typedef _Float16 f16x8 __attribute__((ext_vector_type(8)));
typedef _Float16 f16x4v __attribute__((ext_vector_type(4)));
typedef float f32x4 __attribute__((ext_vector_type(4)));

#define WV_THREADS 256
#define DROW 4160   // per-row float stride of packed d1..d9 (16B-aligned levels)
#define NSPLIT 32
#define KCHUNK 1024
#define GEMM_BM 256

// reconstruction filters
#define L0 0.23037781330885523f
#define L1 0.7148465705525415f
#define L2f 0.6308807679295904f
#define L3 -0.02798376941698385f
#define L4 -0.18703481171888114f
#define L5 0.030841381835986965f
#define L6 0.032883011666982945f
#define L7 -0.010597401784997278f

#define H0 -0.010597401784997278f
#define H1 -0.032883011666982945f
#define H2 0.030841381835986965f
#define H3 0.18703481171888114f
#define H4 -0.02798376941698385f
#define H5 -0.6308807679295904f
#define H6 0.7148465705525415f
#define H7 -0.23037781330885523f

__constant__ constexpr int cNL[10]   = {4096, 2051, 1029, 518, 262, 134, 70, 38, 22, 14};
// 16B-aligned packing; pads absorb window over-reads (>=2 floats each level)
__constant__ constexpr int cDOFF[10] = {0, 0, 2052, 3084, 3604, 3868, 4004, 4076, 4116, 4140};

__device__ __forceinline__ int ext_idx(int j, int n) {
  return (j < 6) ? (5 - j) : ((j < n + 6) ? (j - 6) : (2 * n + 5 - j));
}

// one DWT level, 2 outputs per thread, stride-1 lanes. (analysis, unchanged)
__device__ __forceinline__ void dwt2(const float* a, float* anext, float* d,
                                     int n, int m, bool store_a) {
  const int ng = (m + 1) >> 1;
  for (int g = threadIdx.x; g < ng; g += WV_THREADS) {
    float w[10];
    if (g >= 2 && 4 * g + 9 <= n + 5) {
      const float2* af = (const float2*)a + (2 * g - 3);
      float2 b0 = af[0], b1 = af[1], b2 = af[2], b3 = af[3], b4 = af[4];
      w[0] = b0.x; w[1] = b0.y; w[2] = b1.x; w[3] = b1.y; w[4] = b2.x;
      w[5] = b2.y; w[6] = b3.x; w[7] = b3.y; w[8] = b4.x; w[9] = b4.y;
    } else {
#pragma unroll
      for (int q = 0; q < 10; ++q) {
        int j = 4 * g + q;
        int jm = n + 12;
        if (j > jm) j = jm;
        w[q] = a[ext_idx(j, n)];
      }
    }
    float sl0 = w[0]*L0 + w[1]*L1 + w[2]*L2f + w[3]*L3 + w[4]*L4 + w[5]*L5 + w[6]*L6 + w[7]*L7;
    float sh0 = w[0]*H0 + w[1]*H1 + w[2]*H2  + w[3]*H3 + w[4]*H4 + w[5]*H5 + w[6]*H6 + w[7]*H7;
    float sl1 = w[2]*L0 + w[3]*L1 + w[4]*L2f + w[5]*L3 + w[6]*L4 + w[7]*L5 + w[8]*L6 + w[9]*L7;
    float sh1 = w[2]*H0 + w[3]*H1 + w[4]*H2  + w[5]*H3 + w[6]*H4 + w[7]*H5 + w[8]*H6 + w[9]*H7;
    if (2 * g + 1 < m) {
      if (store_a) *(float2*)(anext + 2 * g) = make_float2(sl0, sl1);
      *(float2*)(d + 2 * g) = make_float2(sh0, sh1);
    } else {
      if (store_a) anext[2 * g] = sl0;
      d[2 * g] = sh0;
    }
  }
}

// ---------------------------------------------------------------------------
// Swizzled LDS float4 slot accessors: slot u -> u ^ ((u>>3)&7). Bijective
// within each aligned 8-slot (128B) row; conflict-free b128 reads/writes.
#define SWZ(u) ((u) ^ (((u) >> 3) & 7))
__device__ __forceinline__ const float4* lds4c(const float* b, int s) {
  return (const float4*)b + SWZ(s);
}
__device__ __forceinline__ float4* lds4(float* b, int s) {
  return (float4*)b + SWZ(s);
}

// ---------------------------------------------------------------------------
// IDWT level primitives (register arrays, fully unrolled).
template <int NP>
__device__ __forceinline__ void lvlL(const float* a, float* v) {  // nocd
#pragma unroll
  for (int q = 0; q < NP; ++q) {
    v[2*q]   = a[q+3]*L0 + a[q+2]*L2f + a[q+1]*L4 + a[q]*L6;
    v[2*q+1] = a[q+3]*L1 + a[q+2]*L3  + a[q+1]*L5 + a[q]*L7;
  }
}
template <int NP>
__device__ __forceinline__ void lvlH(const float* d, float* v) {  // init (cd only)
#pragma unroll
  for (int q = 0; q < NP; ++q) {
    v[2*q]   = d[q+3]*H0 + d[q+2]*H2 + d[q+1]*H4 + d[q]*H6;
    v[2*q+1] = d[q+3]*H1 + d[q+2]*H3 + d[q+1]*H5 + d[q]*H7;
  }
}
template <int NP>
__device__ __forceinline__ void lvlLH(const float* a, const float* d, float* v) {  // withcd
#pragma unroll
  for (int q = 0; q < NP; ++q) {
    v[2*q]   = a[q+3]*L0 + a[q+2]*L2f + a[q+1]*L4 + a[q]*L6
             + d[q+3]*H0 + d[q+2]*H2  + d[q+1]*H4 + d[q]*H6;
    v[2*q+1] = a[q+3]*L1 + a[q+2]*L3  + a[q+1]*L5 + a[q]*L7
             + d[q+3]*H1 + d[q+2]*H3  + d[q+1]*H5 + d[q]*H7;
  }
}

// global window readers
__device__ __forceinline__ void g8f2(const float* p, int s, float* w) {  // s even
#pragma unroll
  for (int i = 0; i < 4; ++i) {
    float2 v = *(const float2*)(p + s + 2 * i);
    w[2*i] = v.x; w[2*i+1] = v.y;
  }
}
__device__ __forceinline__ void g12f4(const float* p, int s, float* w) {  // s%4==0
#pragma unroll
  for (int i = 0; i < 3; ++i) {
    float4 v = *(const float4*)(p + s + 4 * i);
    w[4*i] = v.x; w[4*i+1] = v.y; w[4*i+2] = v.z; w[4*i+3] = v.w;
  }
}

// relu + f16 store of 16 interleaved e/o values
__device__ __forceinline__ void store16(_Float16* outg, int t, const float* v) {
  f16x8 h0, h1;
#pragma unroll
  for (int i = 0; i < 8; ++i) h0[i] = (_Float16)fmaxf(v[i], 0.f);
#pragma unroll
  for (int i = 0; i < 8; ++i) h1[i] = (_Float16)fmaxf(v[8 + i], 0.f);
  *(f16x8*)(outg + 16 * t) = h0;
  *(f16x8*)(outg + 16 * t + 8) = h1;
}

// ---------------------------------------------------------------------------
// Single-stage cascades for L2/L3/L4 (no LDS, no barrier). Verified R3.
__device__ __forceinline__ void fin2(const float* d2, const float* d1, _Float16* og) {
  const int t = threadIdx.x;
  float dw[12];  g12f4(d2, 4 * t, dw);
  float mid[12]; lvlH<6>(dw, mid);           // 2052-arr vals [8t, 8t+12)
  float d1w[12]; g12f4(d1, 8 * t, d1w);
  float v[16];   lvlLH<8>(mid, d1w, v);      // final with cd = d1
  store16(og, t, v);
}

__device__ __forceinline__ void fin3(const float* d3, const float* d2, _Float16* og) {
  const int t = threadIdx.x;
  float dw[8];   g8f2(d3, 2 * t, dw);        // d3[2t..2t+7]
  float v0[10];  lvlH<5>(dw, v0);            // init vals [4t, 4t+10)
  float d2w[12]; g12f4(d2, 4 * t, d2w);
  float v1[12];  lvlLH<6>(v0, d2w, v1);      // wc vals [8t, 8t+12)
  float v[16];   lvlL<8>(v1, v);
  store16(og, t, v);
}

__device__ __forceinline__ void fin4(const float* d4, const float* d3, _Float16* og) {
  const int t = threadIdx.x;
  float dw[7];
#pragma unroll
  for (int i = 0; i < 7; ++i) dw[i] = d4[t + i];   // d4[t..t+6]
  float v0[8];   lvlH<4>(dw, v0);            // [2t, 2t+8)
  float d3w[8];  g8f2(d3, 2 * t, d3w);
  float v1[10];  lvlLH<5>(v0, d3w, v1);      // [4t, 4t+10)
  float v2[12];  lvlL<6>(v1, v2);            // [8t, 8t+12)
  float v[16];   lvlL<8>(v2, v);
  store16(og, t, v);
}

// ---------------------------------------------------------------------------
// R1 proven multi-stage machinery for L5..L9.
template <bool HAS_CA, bool HAS_CD, bool FINAL, int N>
__device__ __forceinline__ void step16(const float* ca, const float* cd,
                                       float* outl, _Float16* outg) {
  constexpr int npair = N - 3;
  constexpr int ng = (npair + 7) >> 3;
  const int t = threadIdx.x;
  if (t >= ng) return;
  float w[12], v[12];
  if constexpr (HAS_CA) {
    float4 a = *lds4c(ca, 2 * t), b = *lds4c(ca, 2 * t + 1), c = *lds4c(ca, 2 * t + 2);
    w[0]=a.x; w[1]=a.y; w[2]=a.z; w[3]=a.w; w[4]=b.x; w[5]=b.y; w[6]=b.z; w[7]=b.w;
    w[8]=c.x; w[9]=c.y; w[10]=c.z; w[11]=c.w;
  }
  if constexpr (HAS_CD) {
    const float4* p = (const float4*)(cd + 8 * t);
    float4 a = p[0], b = p[1], c = p[2];
    v[0]=a.x; v[1]=a.y; v[2]=a.z; v[3]=a.w; v[4]=b.x; v[5]=b.y; v[6]=b.z; v[7]=b.w;
    v[8]=c.x; v[9]=c.y; v[10]=c.z; v[11]=c.w;
  }
  float E[8], O[8];
#pragma unroll
  for (int pp = 0; pp < 8; ++pp) {
    float e = 0.f, o = 0.f;
    if constexpr (HAS_CA) {
      e = w[pp+3]*L0 + w[pp+2]*L2f + w[pp+1]*L4 + w[pp]*L6;
      o = w[pp+3]*L1 + w[pp+2]*L3  + w[pp+1]*L5 + w[pp]*L7;
    }
    if constexpr (HAS_CD) {
      e += v[pp+3]*H0 + v[pp+2]*H2 + v[pp+1]*H4 + v[pp]*H6;
      o += v[pp+3]*H1 + v[pp+2]*H3 + v[pp+1]*H5 + v[pp]*H7;
    }
    E[pp] = e; O[pp] = o;
  }
  if constexpr (FINAL) {
    float vv[16];
#pragma unroll
    for (int q = 0; q < 8; ++q) { vv[2*q] = E[q]; vv[2*q+1] = O[q]; }
    store16(outg, t, vv);
  } else {
#pragma unroll
    for (int j = 0; j < 4; ++j) {
      const int p2 = 8 * t + 2 * j;
      if (p2 + 1 < npair) {
        *lds4(outl, 4 * t + j) = make_float4(E[2*j], O[2*j], E[2*j+1], O[2*j+1]);
      } else if (p2 < npair) {
        *(float2*)lds4(outl, 4 * t + j) = make_float2(E[2*j], O[2*j]);
      }
    }
  }
}

// Two fused no-cd stages from a 12-float window w (= cur[4t..4t+11]).
__device__ __forceinline__ void nocd2_core(const float w[12], float r[11],
                                           float E[8], float O[8]) {
#pragma unroll
  for (int h = 0; h < 6; ++h) {
    float e = w[h+3]*L0 + w[h+2]*L2f + w[h+1]*L4 + w[h]*L6;
    float o = w[h+3]*L1 + w[h+2]*L3  + w[h+1]*L5 + w[h]*L7;
    r[2*h] = e;
    if (2*h + 1 < 11) r[2*h+1] = o;
  }
#pragma unroll
  for (int pp = 0; pp < 8; ++pp) {
    E[pp] = r[pp+3]*L0 + r[pp+2]*L2f + r[pp+1]*L4 + r[pp]*L6;
    O[pp] = r[pp+3]*L1 + r[pp+2]*L3  + r[pp+1]*L5 + r[pp]*L7;
  }
}

// PAIR: two no-cd IDWT steps fused, input LDS len N1 -> output LDS.
template <int N1>
__device__ __forceinline__ void pair16(const float* cur, float* outl) {
  constexpr int N2 = (2 * N1 - 6 == 1030) ? 1029 : (2 * N1 - 6);
  constexpr int np2 = N2 - 3;
  constexpr int ng = (np2 + 7) >> 3;
  const int t = threadIdx.x;
  if (t >= ng) return;
  float w[12];
  float4 a = *lds4c(cur, t), b = *lds4c(cur, t + 1), c = *lds4c(cur, t + 2);
  w[0]=a.x; w[1]=a.y; w[2]=a.z; w[3]=a.w; w[4]=b.x; w[5]=b.y; w[6]=b.z; w[7]=b.w;
  w[8]=c.x; w[9]=c.y; w[10]=c.z; w[11]=c.w;
  float r[11], E[8], O[8];
  nocd2_core(w, r, E, O);
#pragma unroll
  for (int j = 0; j < 4; ++j) {
    const int p2 = 8 * t + 2 * j;
    if (p2 + 1 < np2) {
      *lds4(outl, 4 * t + j) = make_float4(E[2*j], O[2*j], E[2*j+1], O[2*j+1]);
    } else if (p2 < np2) {
      *(float2*)lds4(outl, 4 * t + j) = make_float2(E[2*j], O[2*j]);
    }
  }
}

// FINPAIR: no-cd stage (input len 1029) fused with the final stage.
__device__ __forceinline__ void finpair16(const float* cur, _Float16* outg) {
  const int t = threadIdx.x;
  float w[12];
  float4 a = *lds4c(cur, t), b = *lds4c(cur, t + 1), c = *lds4c(cur, t + 2);
  w[0]=a.x; w[1]=a.y; w[2]=a.z; w[3]=a.w; w[4]=b.x; w[5]=b.y; w[6]=b.z; w[7]=b.w;
  w[8]=c.x; w[9]=c.y; w[10]=c.z; w[11]=c.w;
  float r[11], E[8], O[8];
  nocd2_core(w, r, E, O);
  float vv[16];
#pragma unroll
  for (int q = 0; q < 8; ++q) { vv[2*q] = E[q]; vv[2*q+1] = O[q]; }
  store16(outg, t, vv);
}

// INITPAIR: init (e/o from d_L via H) fused with the with-cd stage.
template <int NL, int NLm1>
__device__ __forceinline__ void initpair16(const float* cdL, const float* cdm,
                                           float* outl) {
  constexpr int np2 = NLm1 - 3;
  constexpr int ng = (np2 + 7) >> 3;
  const int t = threadIdx.x;
  if (t >= ng) return;
  float w[12];
  {
    const float4* p = (const float4*)(cdL + 4 * t);
    float4 a = p[0], b = p[1], c = p[2];
    w[0]=a.x; w[1]=a.y; w[2]=a.z; w[3]=a.w; w[4]=b.x; w[5]=b.y; w[6]=b.z; w[7]=b.w;
    w[8]=c.x; w[9]=c.y; w[10]=c.z; w[11]=c.w;
  }
  float r[11];
#pragma unroll
  for (int h = 0; h < 6; ++h) {
    float e = w[h+3]*H0 + w[h+2]*H2 + w[h+1]*H4 + w[h]*H6;
    float o = w[h+3]*H1 + w[h+2]*H3 + w[h+1]*H5 + w[h]*H7;
    r[2*h] = e;
    if (2*h + 1 < 11) r[2*h+1] = o;
  }
  float v[12];
  {
    const float4* p = (const float4*)(cdm + 8 * t);
    float4 a = p[0], b = p[1], c = p[2];
    v[0]=a.x; v[1]=a.y; v[2]=a.z; v[3]=a.w; v[4]=b.x; v[5]=b.y; v[6]=b.z; v[7]=b.w;
    v[8]=c.x; v[9]=c.y; v[10]=c.z; v[11]=c.w;
  }
  float E[8], O[8];
#pragma unroll
  for (int pp = 0; pp < 8; ++pp) {
    E[pp] = r[pp+3]*L0 + r[pp+2]*L2f + r[pp+1]*L4 + r[pp]*L6
          + v[pp+3]*H0 + v[pp+2]*H2  + v[pp+1]*H4 + v[pp]*H6;
    O[pp] = r[pp+3]*L1 + r[pp+2]*L3  + r[pp+1]*L5 + r[pp]*L7
          + v[pp+3]*H1 + v[pp+2]*H3  + v[pp+1]*H5 + v[pp]*H7;
  }
#pragma unroll
  for (int j = 0; j < 4; ++j) {
    const int p2 = 8 * t + 2 * j;
    if (p2 + 1 < np2) {
      *lds4(outl, 4 * t + j) = make_float4(E[2*j], O[2*j], E[2*j+1], O[2*j+1]);
    } else if (p2 < np2) {
      *(float2*)lds4(outl, 4 * t + j) = make_float2(E[2*j], O[2*j]);
    }
  }
}

// ---------------------------------------------------------------------------
// Fused: blocks [0,2048) = analysis rows; blocks [2048, 2048+6144) = W0 cvt.
__global__ __launch_bounds__(WV_THREADS) void wv_analysis_cvt(
    const float* __restrict__ x, float* __restrict__ dG,
    const float* __restrict__ W0, _Float16* __restrict__ Bw) {
  __shared__ float r1[4104];
  __shared__ float r2[2056];
  const int tid = threadIdx.x;

  if (blockIdx.x >= 2048) {  // ---- cvt path ----
    size_t i = ((size_t)(blockIdx.x - 2048) * 256 + tid) * 4;
    int rowc = (int)(i >> 15);
    f16x4v h;
    if (rowc < 181) {
      const float4 v = *(const float4*)(W0 + i);
      h[0] = (_Float16)v.x; h[1] = (_Float16)v.y;
      h[2] = (_Float16)v.z; h[3] = (_Float16)v.w;
    } else {
      h[0] = (_Float16)0.f; h[1] = (_Float16)0.f;
      h[2] = (_Float16)0.f; h[3] = (_Float16)0.f;
    }
    *(f16x4v*)(Bw + i) = h;
    return;
  }

  const int NLa[10]  = {4096, 2051, 1029, 518, 262, 134, 70, 38, 22, 14};
  const int DOFF[10] = {0, 0, 2052, 3084, 3604, 3868, 4004, 4076, 4116, 4140};
  const int LOFF[10] = {0, 0, 1036, 520, 2068, 1040, 2332, 1176, 2404, 1216};
  const int row = blockIdx.x;

  const float4* xr = (const float4*)(x + (size_t)row * 4096);
  for (int i = tid; i < 1024; i += WV_THREADS) ((float4*)r1)[i] = xr[i];
  __syncthreads();

  float* dr = dG + (size_t)row * DROW;
  dwt2(r1, r2, dr + DOFF[1], NLa[0], NLa[1], true);
  __syncthreads();
  const float* ap = r2;
  float* an = r1;
  for (int lev = 2; lev <= 9; ++lev) {
    float* dbuf = ((lev & 1) ? r2 : r1) + LOFF[lev];
    dwt2(ap, an, dbuf, NLa[lev - 1], NLa[lev], lev < 9);
    __syncthreads();
    const float* t = ap; ap = an; an = (float*)t;
  }
  for (int lev = 2; lev <= 9; ++lev) {
    const float* src = ((lev & 1) ? r2 : r1) + LOFF[lev];
    float* dst = dr + DOFF[lev];
    const int n = NLa[lev];
    for (int i = 2 * tid; i + 1 < n; i += 2 * WV_THREADS)
      *(float2*)(dst + i) = *(const float2*)(src + i);
    if ((n & 1) && tid == 0) dst[n - 1] = src[n - 1];
  }
}

// ---------------------------------------------------------------------------
// Synthesis: one block per (row, L=2+blockIdx.y).
// L2-4: single-stage register fins. L5-9: R1 proven cascades.
__global__ __launch_bounds__(WV_THREADS, 8) void wv_synth(
    const float* __restrict__ dG, _Float16* __restrict__ A) {
  __shared__ alignas(16) float s1[2080];
  __shared__ alignas(16) float s2[2080];
  const int row = blockIdx.x;
  const float* dr = dG + (size_t)row * DROW;
  _Float16* og = A + (size_t)row * 32768 + (size_t)blockIdx.y * 4096;
  switch (blockIdx.y) {
    case 0: fin2(dr + cDOFF[2], dr + cDOFF[1], og); break;
    case 1: fin3(dr + cDOFF[3], dr + cDOFF[2], og); break;
    case 2: fin4(dr + cDOFF[4], dr + cDOFF[3], og); break;
    case 3:  // L5
      initpair16<cNL[5], cNL[4]>(dr + cDOFF[5], dr + cDOFF[4], s1);
      __syncthreads();
      pair16<518>(s1, s2); __syncthreads();
      step16<true, false, true, 2051>(s2, nullptr, nullptr, og);
      break;
    case 4:  // L6
      initpair16<cNL[6], cNL[5]>(dr + cDOFF[6], dr + cDOFF[5], s1);
      __syncthreads();
      pair16<262>(s1, s2); __syncthreads();
      finpair16(s2, og);
      break;
    case 5:  // L7
      initpair16<cNL[7], cNL[6]>(dr + cDOFF[7], dr + cDOFF[6], s1);
      __syncthreads();
      pair16<134>(s1, s2); __syncthreads();
      pair16<518>(s2, s1); __syncthreads();
      step16<true, false, true, 2051>(s1, nullptr, nullptr, og);
      break;
    case 6:  // L8
      initpair16<cNL[8], cNL[7]>(dr + cDOFF[8], dr + cDOFF[7], s1);
      __syncthreads();
      pair16<70>(s1, s2); __syncthreads();
      pair16<262>(s2, s1); __syncthreads();
      finpair16(s1, og);
      break;
    default:  // L9
      initpair16<cNL[9], cNL[8]>(dr + cDOFF[9], dr + cDOFF[8], s1);
      __syncthreads();
      pair16<38>(s1, s2); __syncthreads();
      pair16<134>(s2, s1); __syncthreads();
      pair16<518>(s1, s2); __syncthreads();
      step16<true, false, true, 2051>(s2, nullptr, nullptr, og);
      break;
  }
}

// ---------------------------------------------------------------------------
__device__ __forceinline__ void load_lds16(const void* g, void* l) {
  __builtin_amdgcn_global_load_lds((__attribute__((address_space(1))) unsigned int*)g,
                                   (__attribute__((address_space(3))) unsigned int*)l,
                                   16, 0, 0);
}

// C(2048x192) += A(2048x32768,f16) * Bw(192x32768,f16)^T, fp32 split-K
// partials. BM=256, 8 waves, grid (8 m, 32 k) = 256 blocks = 1/CU.
// Counted-vmcnt double-buffer pipeline (T4): per iter,
//   stage(ks+1) [7 global_load_lds/thread] -> s_waitcnt vmcnt(7)
//   (tile ks resident; tile ks+1's loads stay in flight across barrier)
//   -> s_barrier -> MFMA on buf[ks&1] -> s_barrier (RAW hazard only).
// Epilogue peels last tile with vmcnt(0). Never drains in steady state.
__global__ __launch_bounds__(512, 2) void gemm_kernel(
    const _Float16* __restrict__ A, const _Float16* __restrict__ Bw,
    float* __restrict__ P) {
  __shared__ _Float16 As[2][GEMM_BM * 64];  // 2 x 32 KB
  __shared__ _Float16 Bs[2][192 * 64];      // 2 x 24 KB  (total 112 KB)
  const int tid = threadIdx.x;
  const int lane = tid & 63;
  const int wave = tid >> 6;          // 0..7
  const int m0 = blockIdx.x * GEMM_BM;
  const int k_idx = blockIdx.y;
  const int k0 = k_idx * KCHUNK;

  f32x4 acc[2][12];
#pragma unroll
  for (int mt = 0; mt < 2; ++mt)
#pragma unroll
    for (int nt = 0; nt < 12; ++nt) acc[mt][nt] = (f32x4){0.f, 0.f, 0.f, 0.f};

  // stage tile ks into buffer b: A 32KB (4 insts/thread), B 24KB (3/thread)
  auto stage = [&](int ks, int b) {
    const int kbase = k0 + (ks << 6);
#pragma unroll
    for (int t = 0; t < 4; ++t) {
      int c = wave * 4 + t;
      int g = (c << 6) + lane;
      int r = g >> 3, cs = g & 7;
      const _Float16* gp = A + (size_t)(m0 + r) * 32768 + kbase + ((cs ^ (r & 7)) << 3);
      load_lds16(gp, (char*)As[b] + ((size_t)c << 10));
    }
#pragma unroll
    for (int t = 0; t < 3; ++t) {
      int c = wave * 3 + t;
      int g = (c << 6) + lane;
      int r = g >> 3, cs = g & 7;
      const _Float16* gp = Bw + (size_t)r * 32768 + kbase + ((cs ^ (r & 7)) << 3);
      load_lds16(gp, (char*)Bs[b] + ((size_t)c << 10));
    }
  };

  auto compute = [&](int cur) {
#pragma unroll
    for (int kk = 0; kk < 2; ++kk) {
      const int chunk = kk * 4 + (lane >> 4);
      f16x8 af[2];
#pragma unroll
      for (int mt = 0; mt < 2; ++mt) {
        int r = wave * 32 + mt * 16 + (lane & 15);
        af[mt] = *(const f16x8*)(As[cur] + r * 64 + ((chunk ^ (r & 7)) << 3));
      }
#pragma unroll
      for (int nt = 0; nt < 12; ++nt) {
        int rb = nt * 16 + (lane & 15);
        f16x8 bf = *(const f16x8*)(Bs[cur] + rb * 64 + ((chunk ^ (rb & 7)) << 3));
        acc[0][nt] = __builtin_amdgcn_mfma_f32_16x16x32_f16(af[0], bf, acc[0][nt], 0, 0, 0);
        acc[1][nt] = __builtin_amdgcn_mfma_f32_16x16x32_f16(af[1], bf, acc[1][nt], 0, 0, 0);
      }
    }
  };

  constexpr int NT = KCHUNK >> 6;   // 16 tiles
  stage(0, 0);
  for (int ks = 0; ks < NT - 1; ++ks) {
    stage(ks + 1, (ks + 1) & 1);
    asm volatile("s_waitcnt vmcnt(7)" ::: "memory");  // tile ks resident
    __builtin_amdgcn_s_barrier();
    compute(ks & 1);
    __builtin_amdgcn_s_barrier();    // all reads of buf[ks&1] done before
                                     // next iter's stage overwrites it
  }
  asm volatile("s_waitcnt vmcnt(0)" ::: "memory");    // last tile resident
  __builtin_amdgcn_s_barrier();
  compute((NT - 1) & 1);

  float* Pp = P + ((size_t)k_idx * 2048 + m0) * 192;
#pragma unroll
  for (int mt = 0; mt < 2; ++mt)
#pragma unroll
    for (int nt = 0; nt < 12; ++nt)
#pragma unroll
      for (int r4 = 0; r4 < 4; ++r4) {
        int rr = wave * 32 + mt * 16 + ((lane >> 4) << 2) + r4;
        int cc = nt * 16 + (lane & 15);
        Pp[(size_t)rr * 192 + cc] = acc[mt][nt][r4];
      }
}

// ---------------------------------------------------------------------------
// P reduce: 4 wave-groups x 8 splits, coalesced; then layers 1..2. (R8 form.)
__global__ __launch_bounds__(256) void mlp_kernel(
    const float* __restrict__ P, const float* __restrict__ b0,
    const float* __restrict__ W1, const float* __restrict__ b1,
    const float* __restrict__ W2, const float* __restrict__ b2,
    float* __restrict__ out) {
  __shared__ float part[4][193];
  __shared__ float h1[192];
  __shared__ float h2[13];
  const int row = blockIdx.x;
  const int t = threadIdx.x;
  const int g = t >> 6;
  const int l = t & 63;

  float a0 = 0.f, a1 = 0.f, a2 = 0.f;
  for (int si = 0; si < NSPLIT / 4; ++si) {
    int s = g + (si << 2);
    const float* Pr = P + ((size_t)s * 2048 + row) * 192;
    a0 += Pr[l]; a1 += Pr[64 + l]; a2 += Pr[128 + l];
  }
  part[g][l] = a0; part[g][64 + l] = a1; part[g][128 + l] = a2;
  __syncthreads();

  if (t < 192) {
    float v = part[0][t] + part[1][t] + part[2][t] + part[3][t];
    h1[t] = (t < 181) ? fmaxf(v + b0[t], 0.f) : 0.f;
  }
  __syncthreads();

#pragma unroll
  for (int r = 0; r < 4; ++r) {
    int j = g + (r << 2);
    if (j < 13) {
      float v = 0.f;
#pragma unroll
      for (int q = 0; q < 3; ++q) {
        int n = l + (q << 6);
        if (n < 181) v += h1[n] * W1[j * 181 + n];
      }
      for (int off = 32; off >= 1; off >>= 1) v += __shfl_down(v, off);
      if (l == 0) h2[j] = fmaxf(v + b1[j], 0.f);
    }
  }
  __syncthreads();

  if (t < 10) {
    float c = b2[t];
#pragma unroll
    for (int j = 0; j < 13; ++j) c += h2[j] * W2[t * 13 + j];
    out[(size_t)row * 10 + t] = c;
  }
}

// ---------------------------------------------------------------------------
extern "C" void kernel_launch(void* const* d_in, const int* in_sizes, int n_in,
                              void* d_out, int out_size, void* d_ws, size_t ws_size,
                              hipStream_t stream) {
  const float* x1 = (const float*)d_in[0];
  const float* W0 = (const float*)d_in[3];
  const float* b0 = (const float*)d_in[4];
  const float* W1 = (const float*)d_in[5];
  const float* b1 = (const float*)d_in[6];
  const float* W2 = (const float*)d_in[7];
  const float* b2 = (const float*)d_in[8];
  float* out = (float*)d_out;

  char* ws = (char*)d_ws;
  const size_t A_BYTES = (size_t)2048 * 32768 * 2;
  const size_t B_BYTES = (size_t)192 * 32768 * 2;
  _Float16* Afeat = (_Float16*)ws;
  _Float16* Bw = (_Float16*)(ws + A_BYTES);
  // D (2048*4160*4 = 34 MB) aliases P (50 MB): D dead before gemm writes P.
  float* Dq = (float*)(ws + A_BYTES + B_BYTES);
  float* P = (float*)(ws + A_BYTES + B_BYTES);

  wv_analysis_cvt<<<2048 + 6144, WV_THREADS, 0, stream>>>(x1, Dq, W0, Bw);
  dim3 sg(2048, 8);
  wv_synth<<<sg, WV_THREADS, 0, stream>>>(Dq, Afeat);
  dim3 gg(2048 / GEMM_BM, NSPLIT);
  gemm_kernel<<<gg, 512, 0, stream>>>(Afeat, Bw, P);
  mlp_kernel<<<2048, 256, 0, stream>>>(P, b0, W1, b1, W2, b2, out);
}